// Round 2
// baseline (445.453 us; speedup 1.0000x reference)
//
#include <hip/hip_runtime.h>
#include <hip/hip_bf16.h>

#define L2E 1.4426950408889634f

#if defined(__has_builtin)
#if __has_builtin(__builtin_amdgcn_exp2f)
#define EXP2(x) __builtin_amdgcn_exp2f(x)
#else
#define EXP2(x) exp2f(x)
#endif
#else
#define EXP2(x) exp2f(x)
#endif

typedef __attribute__((ext_vector_type(8))) short bf16x8;
typedef __attribute__((ext_vector_type(4))) float f32x4;

__device__ __forceinline__ void gld_lds16(const void* g, void* l) {
  __builtin_amdgcn_global_load_lds(
      (const __attribute__((address_space(1))) void*)g,
      (__attribute__((address_space(3))) void*)l, 16, 0, 0);
}

__device__ __forceinline__ unsigned bf16rne(float f) {
  unsigned u = __float_as_uint(f);
  return (u + 0x7fffu + ((u >> 16) & 1u)) >> 16;
}

// Kernel A: L2-normalize embedding table -> packed bf16 (2 per uint32).
__global__ __launch_bounds__(256) void knrm_norm(const float* __restrict__ emb,
                                                 unsigned* __restrict__ embN) {
  const int lane = threadIdx.x & 63;
  int gw = blockIdx.x * 4 + (threadIdx.x >> 6);
  const int nW = gridDim.x * 4;
  for (int r = gw; r < 50000; r += nW) {
    float2 v = *(const float2*)(emb + (size_t)r * 128 + lane * 2);
    float ss = v.x * v.x + v.y * v.y;
#pragma unroll
    for (int m = 1; m < 64; m <<= 1) ss += __shfl_xor(ss, m, 64);
    float sc = 1.0f / fmaxf(sqrtf(ss), 1e-12f);
    embN[(size_t)r * 64 + lane] = bf16rne(v.x * sc) | (bf16rne(v.y * sc) << 16);
  }
}

// Kernel B: per batch item: gather q(64) + d(256) bf16 rows to LDS,
// mm^T via mfma_f32_16x16x32_bf16, factorized 20-kernel accumulation,
// exact-match kernel via integer token compare, then fused MLP.
__global__ __launch_bounds__(256, 3) void knrm_main(
    const int* __restrict__ query, const int* __restrict__ doc,
    const unsigned* __restrict__ embN,
    const float* __restrict__ W1, const float* __restrict__ b1,
    const float* __restrict__ W2, const float* __restrict__ b2,
    const float* __restrict__ W3, const float* __restrict__ b3,
    float* __restrict__ out) {
  __shared__ __align__(16) char qtile[64 * 256];    // 16KB, reused as kmbuf later
  __shared__ __align__(16) char dtile[128 * 256];   // 32KB (one half of docs)
  __shared__ int qtok[64];
  __shared__ int dtok[256];
  __shared__ float km2[4][21];
  __shared__ float kmv[21];
  __shared__ float x1[10];
  __shared__ float x2[5];
  float* kmbuf = (float*)qtile;  // [64][21] raw kernel sums (overlay, post-compute)

  const int b = blockIdx.x;
  const int tid = threadIdx.x;
  const int w = tid >> 6;
  const int lane = tid & 63;
  const int lo = lane & 15, hi = lane >> 4;
  const char* embB = (const char*)embN;  // 256 B per vocab row (128 bf16)

  // ---- token staging (plain LDS writes) ----
  if (tid < 64) qtok[tid] = query[b * 64 + tid];
  dtok[tid] = doc[b * 256 + tid];

  // ---- stage q tile (wave w: rows 16w..16w+15) + d half 0 (rows 32w..32w+31)
  // LDS layout: row-major 256B rows, 16B slots XOR-swizzled: phys_slot = log_slot ^ (row&7).
  // global_load_lds writes linearly (base + lane*16), so we pre-swizzle the SOURCE slot.
#pragma unroll
  for (int it = 0; it < 4; ++it) {
    int r = w * 16 + it * 4 + hi;
    int tok = query[b * 64 + r];
    int slot = lo ^ (r & 7);
    gld_lds16(embB + (size_t)tok * 256 + slot * 16, qtile + (w * 16 + it * 4) * 256);
  }
#pragma unroll
  for (int it = 0; it < 8; ++it) {
    int rl = w * 32 + it * 4 + hi;  // local dtile row = doc 0..127
    int tok = doc[b * 256 + rl];
    int slot = lo ^ (rl & 7);
    gld_lds16(embB + (size_t)tok * 256 + slot * 16, dtile + (w * 32 + it * 4) * 256);
  }
  asm volatile("s_waitcnt vmcnt(0)" ::: "memory");
  __syncthreads();

  // ---- load Q fragments (B-operand: col = lo = q, k = 8*hi+e), once ----
  bf16x8 bq[4];
#pragma unroll
  for (int kk = 0; kk < 4; ++kk) {
    int slot = (kk * 4 + hi) ^ (lo & 7);
    bq[kk] = *(const bf16x8*)(qtile + (w * 16 + lo) * 256 + slot * 16);
  }

  float acc20[20];
#pragma unroll
  for (int j = 0; j < 20; ++j) acc20[j] = 0.0f;

  const float cA = -50.0f * L2E;   // for |v|*(95-50|v|) exponent (log2 domain)
  const float cB = 95.0f * L2E;
  const float cR = -10.0f * L2E;

#pragma unroll 1
  for (int h = 0; h < 2; ++h) {
    if (h == 1) {
      __syncthreads();  // everyone done reading dtile half 0
#pragma unroll
      for (int it = 0; it < 8; ++it) {
        int rl = w * 32 + it * 4 + hi;
        int tok = doc[b * 256 + 128 + rl];
        int slot = lo ^ (rl & 7);
        gld_lds16(embB + (size_t)tok * 256 + slot * 16, dtile + (w * 32 + it * 4) * 256);
      }
      asm volatile("s_waitcnt vmcnt(0)" ::: "memory");
      __syncthreads();
    }
#pragma unroll
    for (int dr = 0; dr < 8; ++dr) {
      f32x4 mm = {0.0f, 0.0f, 0.0f, 0.0f};
#pragma unroll
      for (int kk = 0; kk < 4; ++kk) {
        int row = dr * 16 + lo;  // doc row (A-operand: row = lo, k = 8*hi+e)
        int slot = (kk * 4 + hi) ^ (lo & 7);
        bf16x8 a = *(const bf16x8*)(dtile + row * 256 + slot * 16);
        mm = __builtin_amdgcn_mfma_f32_16x16x32_bf16(a, bq[kk], mm, 0, 0, 0);
      }
      // mm[e]: doc = 16*dr + 4*hi + e (this half), q = w*16 + lo
#pragma unroll
      for (int e = 0; e < 4; ++e) {
        float v = mm[e];
        float av = fabsf(v);
        float m1 = fmaf(cA, av, cB);       // (95 - 50|v|)*log2e
        float eA = EXP2(m1 * av);          // p at the max-end mu (0.95*sign)
        float r = EXP2(cR * av);           // ratio exp(-10|v|), <= 1
        bool pos = (v >= 0.0f);
        float qq[20];
        qq[0] = eA;
#pragma unroll
        for (int i = 1; i < 20; ++i) qq[i] = qq[i - 1] * r;
#pragma unroll
        for (int j = 0; j < 20; ++j) acc20[j] += pos ? qq[19 - j] : qq[j];
      }
    }
  }

  // ---- exact-match kernel via integer equality (lane covers docs 64*hi..64*hi+63)
  int myq = qtok[w * 16 + lo];
  int cnt = 0;
#pragma unroll 16
  for (int i = 0; i < 64; ++i) cnt += (dtok[hi * 64 + i] == myq) ? 1 : 0;

  // ---- reduce over hi (lanes 16,32 apart share same q) ----
#pragma unroll
  for (int j = 0; j < 20; ++j) {
    acc20[j] += __shfl_xor(acc20[j], 16, 64);
    acc20[j] += __shfl_xor(acc20[j], 32, 64);
  }
  cnt += __shfl_xor(cnt, 16, 64);
  cnt += __shfl_xor(cnt, 32, 64);

  // qtile LDS is dead (bq in regs since before half-0 compute) -> overlay kmbuf
  if (hi == 0) {
    int q = w * 16 + lo;
#pragma unroll
    for (int j = 0; j < 20; ++j) kmbuf[q * 21 + j] = acc20[j];
    kmbuf[q * 21 + 20] = (float)cnt;
  }
  __syncthreads();

  // ---- km[j] = sum_q log1p(C_j * rawsum) ----
  if (tid < 84) {
    int j = tid % 21, c = tid / 21;
    float Cj = 1.0f;
    if (j < 20) {
      float mu = -0.95f + 0.1f * (float)j;
      Cj = EXP2(cA * mu * mu);  // exp(-50*mu^2)
    }
    float s = 0.0f;
    for (int q = 0; q < 16; ++q) s += log1pf(Cj * kmbuf[(c * 16 + q) * 21 + j]);
    km2[c][j] = s;
  }
  __syncthreads();
  if (tid < 21)
    kmv[tid] = fmaxf(km2[0][tid] + km2[1][tid] + km2[2][tid] + km2[3][tid], 0.0f);
  __syncthreads();
  if (tid < 10) {
    float s = b1[tid];
    for (int j = 0; j < 21; ++j) s = fmaf(W1[tid * 21 + j], kmv[j], s);
    x1[tid] = fmaxf(s, 0.0f);
  }
  __syncthreads();
  if (tid < 5) {
    float s = b2[tid];
    for (int i = 0; i < 10; ++i) s = fmaf(W2[tid * 10 + i], x1[i], s);
    x2[tid] = s;
  }
  __syncthreads();
  if (tid == 0) {
    float s = b3[0];
    for (int i = 0; i < 5; ++i) s = fmaf(W3[i], x2[i], s);
    out[b] = s;
  }
}

extern "C" void kernel_launch(void* const* d_in, const int* in_sizes, int n_in,
                              void* d_out, int out_size, void* d_ws, size_t ws_size,
                              hipStream_t stream) {
  const int* query = (const int*)d_in[0];
  const int* doc = (const int*)d_in[1];
  const float* emb = (const float*)d_in[2];
  const float* W1 = (const float*)d_in[3];
  const float* b1 = (const float*)d_in[4];
  const float* W2 = (const float*)d_in[5];
  const float* b2 = (const float*)d_in[6];
  const float* W3 = (const float*)d_in[7];
  const float* b3 = (const float*)d_in[8];
  float* out = (float*)d_out;
  unsigned* embN = (unsigned*)d_ws;  // 50000*64 uints = 12.8 MB bf16 table

  hipLaunchKernelGGL(knrm_norm, dim3(1024), dim3(256), 0, stream, emb, embN);
  hipLaunchKernelGGL(knrm_main, dim3(1024), dim3(256), 0, stream, query, doc, embN,
                     W1, b1, W2, b2, W3, b3, out);
}

// Round 3
// 444.687 us; speedup vs baseline: 1.0017x; 1.0017x over previous
//
#include <hip/hip_runtime.h>
#include <hip/hip_bf16.h>

#define L2E 1.4426950408889634f

#if defined(__has_builtin)
#if __has_builtin(__builtin_amdgcn_exp2f)
#define EXP2(x) __builtin_amdgcn_exp2f(x)
#else
#define EXP2(x) exp2f(x)
#endif
#else
#define EXP2(x) exp2f(x)
#endif

typedef __attribute__((ext_vector_type(8))) short bf16x8;
typedef __attribute__((ext_vector_type(4))) float f32x4;

__device__ __forceinline__ void gld_lds16(const void* g, void* l) {
  __builtin_amdgcn_global_load_lds(
      (const __attribute__((address_space(1))) void*)g,
      (__attribute__((address_space(3))) void*)l, 16, 0, 0);
}

__device__ __forceinline__ unsigned bf16rne(float f) {
  unsigned u = __float_as_uint(f);
  return (u + 0x7fffu + ((u >> 16) & 1u)) >> 16;
}

// Kernel A: L2-normalize embedding table -> packed bf16 (2 per uint32).
__global__ __launch_bounds__(256) void knrm_norm(const float* __restrict__ emb,
                                                 unsigned* __restrict__ embN) {
  const int lane = threadIdx.x & 63;
  int gw = blockIdx.x * 4 + (threadIdx.x >> 6);
  const int nW = gridDim.x * 4;
  for (int r = gw; r < 50000; r += nW) {
    float2 v = *(const float2*)(emb + (size_t)r * 128 + lane * 2);
    float ss = v.x * v.x + v.y * v.y;
#pragma unroll
    for (int m = 1; m < 64; m <<= 1) ss += __shfl_xor(ss, m, 64);
    float sc = 1.0f / fmaxf(sqrtf(ss), 1e-12f);
    embN[(size_t)r * 64 + lane] = bf16rne(v.x * sc) | (bf16rne(v.y * sc) << 16);
  }
}

// Kernel B: per batch item: gather q(64) + d(256) bf16 rows to LDS,
// mm^T via mfma_f32_16x16x32_bf16, factorized 20-kernel accumulation,
// exact-match kernel via integer token compare, then fused MLP.
__global__ __launch_bounds__(256, 3) void knrm_main(
    const int* __restrict__ query, const int* __restrict__ doc,
    const unsigned* __restrict__ embN,
    const float* __restrict__ W1, const float* __restrict__ b1,
    const float* __restrict__ W2, const float* __restrict__ b2,
    const float* __restrict__ W3, const float* __restrict__ b3,
    float* __restrict__ out) {
  __shared__ __align__(16) char qtile[64 * 256];    // 16KB, reused as kmbuf later
  __shared__ __align__(16) char dtile[128 * 256];   // 32KB (one half of docs)
  __shared__ int qtok[64];
  __shared__ int dtok[256];
  __shared__ float km2[4][21];
  __shared__ float kmv[21];
  __shared__ float x1[10];
  __shared__ float x2[5];
  float* kmbuf = (float*)qtile;  // [64][21] raw kernel sums (overlay, post-compute)

  const int b = blockIdx.x;
  const int tid = threadIdx.x;
  const int w = tid >> 6;
  const int lane = tid & 63;
  const int lo = lane & 15, hi = lane >> 4;
  const char* embB = (const char*)embN;  // 256 B per vocab row (128 bf16)

  // ---- token staging (plain LDS writes) ----
  if (tid < 64) qtok[tid] = query[b * 64 + tid];
  dtok[tid] = doc[b * 256 + tid];

  // ---- stage q tile (wave w: rows 16w..16w+15) + d half 0 (rows 32w..32w+31)
  // LDS layout: row-major 256B rows, 16B slots XOR-swizzled: phys_slot = log_slot ^ (row&7).
  // global_load_lds writes linearly (base + lane*16), so we pre-swizzle the SOURCE slot.
#pragma unroll
  for (int it = 0; it < 4; ++it) {
    int r = w * 16 + it * 4 + hi;
    int tok = query[b * 64 + r];
    int slot = lo ^ (r & 7);
    gld_lds16(embB + (size_t)tok * 256 + slot * 16, qtile + (w * 16 + it * 4) * 256);
  }
#pragma unroll
  for (int it = 0; it < 8; ++it) {
    int rl = w * 32 + it * 4 + hi;  // local dtile row = doc 0..127
    int tok = doc[b * 256 + rl];
    int slot = lo ^ (rl & 7);
    gld_lds16(embB + (size_t)tok * 256 + slot * 16, dtile + (w * 32 + it * 4) * 256);
  }
  asm volatile("s_waitcnt vmcnt(0)" ::: "memory");
  __syncthreads();

  // ---- load Q fragments (B-operand: col = lo = q, k = 8*hi+e), once ----
  bf16x8 bq[4];
#pragma unroll
  for (int kk = 0; kk < 4; ++kk) {
    int slot = (kk * 4 + hi) ^ (lo & 7);
    bq[kk] = *(const bf16x8*)(qtile + (w * 16 + lo) * 256 + slot * 16);
  }

  float acc20[20];
#pragma unroll
  for (int j = 0; j < 20; ++j) acc20[j] = 0.0f;

  const float cA = -50.0f * L2E;   // for |v|*(95-50|v|) exponent (log2 domain)
  const float cB = 95.0f * L2E;
  const float cR = -10.0f * L2E;

#pragma unroll 1
  for (int h = 0; h < 2; ++h) {
    if (h == 1) {
      __syncthreads();  // everyone done reading dtile half 0
#pragma unroll
      for (int it = 0; it < 8; ++it) {
        int rl = w * 32 + it * 4 + hi;
        int tok = doc[b * 256 + 128 + rl];
        int slot = lo ^ (rl & 7);
        gld_lds16(embB + (size_t)tok * 256 + slot * 16, dtile + (w * 32 + it * 4) * 256);
      }
      asm volatile("s_waitcnt vmcnt(0)" ::: "memory");
      __syncthreads();
    }
#pragma unroll
    for (int dr = 0; dr < 8; ++dr) {
      f32x4 mm = {0.0f, 0.0f, 0.0f, 0.0f};
#pragma unroll
      for (int kk = 0; kk < 4; ++kk) {
        int row = dr * 16 + lo;  // doc row (A-operand: row = lo, k = 8*hi+e)
        int slot = (kk * 4 + hi) ^ (lo & 7);
        bf16x8 a = *(const bf16x8*)(dtile + row * 256 + slot * 16);
        mm = __builtin_amdgcn_mfma_f32_16x16x32_bf16(a, bq[kk], mm, 0, 0, 0);
      }
      // mm[e]: doc = 16*dr + 4*hi + e (this half), q = w*16 + lo
#pragma unroll
      for (int e = 0; e < 4; ++e) {
        float v = mm[e];
        float av = fabsf(v);
        float m1 = fmaf(cA, av, cB);       // (95 - 50|v|)*log2e
        float eA = EXP2(m1 * av);          // p at the max-end mu (0.95*sign)
        float r = EXP2(cR * av);           // ratio exp(-10|v|), <= 1
        bool pos = (v >= 0.0f);
        float qq[20];
        qq[0] = eA;
#pragma unroll
        for (int i = 1; i < 20; ++i) qq[i] = qq[i - 1] * r;
#pragma unroll
        for (int j = 0; j < 20; ++j) acc20[j] += pos ? qq[19 - j] : qq[j];
      }
    }
  }

  // ---- exact-match kernel via integer equality (lane covers docs 64*hi..64*hi+63)
  int myq = qtok[w * 16 + lo];
  int cnt = 0;
#pragma unroll 16
  for (int i = 0; i < 64; ++i) cnt += (dtok[hi * 64 + i] == myq) ? 1 : 0;

  // ---- reduce over hi (lanes 16,32 apart share same q) ----
#pragma unroll
  for (int j = 0; j < 20; ++j) {
    acc20[j] += __shfl_xor(acc20[j], 16, 64);
    acc20[j] += __shfl_xor(acc20[j], 32, 64);
  }
  cnt += __shfl_xor(cnt, 16, 64);
  cnt += __shfl_xor(cnt, 32, 64);

  // qtile LDS is dead (bq in regs since before half-0 compute) -> overlay kmbuf
  if (hi == 0) {
    int q = w * 16 + lo;
#pragma unroll
    for (int j = 0; j < 20; ++j) kmbuf[q * 21 + j] = acc20[j];
    kmbuf[q * 21 + 20] = (float)cnt;
  }
  __syncthreads();

  // ---- km[j] = sum_q log1p(C_j * rawsum) ----
  if (tid < 84) {
    int j = tid % 21, c = tid / 21;
    float Cj = 1.0f;
    if (j < 20) {
      float mu = -0.95f + 0.1f * (float)j;
      Cj = EXP2(cA * mu * mu);  // exp(-50*mu^2)
    }
    float s = 0.0f;
    for (int q = 0; q < 16; ++q) s += log1pf(Cj * kmbuf[(c * 16 + q) * 21 + j]);
    km2[c][j] = s;
  }
  __syncthreads();
  if (tid < 21)
    kmv[tid] = fmaxf(km2[0][tid] + km2[1][tid] + km2[2][tid] + km2[3][tid], 0.0f);
  __syncthreads();
  if (tid < 10) {
    float s = b1[tid];
    for (int j = 0; j < 21; ++j) s = fmaf(W1[tid * 21 + j], kmv[j], s);
    x1[tid] = fmaxf(s, 0.0f);
  }
  __syncthreads();
  if (tid < 5) {
    float s = b2[tid];
    for (int i = 0; i < 10; ++i) s = fmaf(W2[tid * 10 + i], x1[i], s);
    x2[tid] = s;
  }
  __syncthreads();
  if (tid == 0) {
    float s = b3[0];
    for (int i = 0; i < 5; ++i) s = fmaf(W3[i], x2[i], s);
    out[b] = s;
  }
}

extern "C" void kernel_launch(void* const* d_in, const int* in_sizes, int n_in,
                              void* d_out, int out_size, void* d_ws, size_t ws_size,
                              hipStream_t stream) {
  const int* query = (const int*)d_in[0];
  const int* doc = (const int*)d_in[1];
  const float* emb = (const float*)d_in[2];
  const float* W1 = (const float*)d_in[3];
  const float* b1 = (const float*)d_in[4];
  const float* W2 = (const float*)d_in[5];
  const float* b2 = (const float*)d_in[6];
  const float* W3 = (const float*)d_in[7];
  const float* b3 = (const float*)d_in[8];
  float* out = (float*)d_out;
  unsigned* embN = (unsigned*)d_ws;  // 50000*64 uints = 12.8 MB bf16 table

  hipLaunchKernelGGL(knrm_norm, dim3(1024), dim3(256), 0, stream, emb, embN);
  hipLaunchKernelGGL(knrm_main, dim3(1024), dim3(256), 0, stream, query, doc, embN,
                     W1, b1, W2, b2, W3, b3, out);
}

// Round 4
// 444.516 us; speedup vs baseline: 1.0021x; 1.0004x over previous
//
#include <hip/hip_runtime.h>
#include <hip/hip_bf16.h>

#define L2E 1.4426950408889634f

#if defined(__has_builtin)
#if __has_builtin(__builtin_amdgcn_exp2f)
#define EXP2(x) __builtin_amdgcn_exp2f(x)
#else
#define EXP2(x) exp2f(x)
#endif
#else
#define EXP2(x) exp2f(x)
#endif

typedef __attribute__((ext_vector_type(8))) short bf16x8;
typedef __attribute__((ext_vector_type(4))) float f32x4;

__device__ __forceinline__ void gld_lds16(const void* g, void* l) {
  __builtin_amdgcn_global_load_lds(
      (const __attribute__((address_space(1))) void*)g,
      (__attribute__((address_space(3))) void*)l, 16, 0, 0);
}

__device__ __forceinline__ unsigned bf16rne(float f) {
  unsigned u = __float_as_uint(f);
  return (u + 0x7fffu + ((u >> 16) & 1u)) >> 16;
}

// Kernel A: L2-normalize embedding table -> packed bf16 (2 per uint32).
__global__ __launch_bounds__(256) void knrm_norm(const float* __restrict__ emb,
                                                 unsigned* __restrict__ embN) {
  const int lane = threadIdx.x & 63;
  int gw = blockIdx.x * 4 + (threadIdx.x >> 6);
  const int nW = gridDim.x * 4;
  for (int r = gw; r < 50000; r += nW) {
    float2 v = *(const float2*)(emb + (size_t)r * 128 + lane * 2);
    float ss = v.x * v.x + v.y * v.y;
#pragma unroll
    for (int m = 1; m < 64; m <<= 1) ss += __shfl_xor(ss, m, 64);
    float sc = 1.0f / fmaxf(sqrtf(ss), 1e-12f);
    embN[(size_t)r * 64 + lane] = bf16rne(v.x * sc) | (bf16rne(v.y * sc) << 16);
  }
}

// Kernel B: per batch item: gather q(64) + d(256) bf16 rows to LDS,
// mm^T via mfma_f32_16x16x32_bf16, factorized 20-kernel accumulation,
// exact-match kernel via integer token compare, then fused MLP.
__global__ __launch_bounds__(256, 3) void knrm_main(
    const int* __restrict__ query, const int* __restrict__ doc,
    const unsigned* __restrict__ embN,
    const float* __restrict__ W1, const float* __restrict__ b1,
    const float* __restrict__ W2, const float* __restrict__ b2,
    const float* __restrict__ W3, const float* __restrict__ b3,
    float* __restrict__ out) {
  __shared__ __align__(16) char qtile[64 * 256];    // 16KB, reused as kmbuf later
  __shared__ __align__(16) char dtile[128 * 256];   // 32KB (one half of docs)
  __shared__ int qtok[64];
  __shared__ int dtok[256];
  __shared__ float km2[4][21];
  __shared__ float kmv[21];
  __shared__ float x1[10];
  __shared__ float x2[5];
  float* kmbuf = (float*)qtile;  // [64][21] raw kernel sums (overlay, post-compute)

  const int b = blockIdx.x;
  const int tid = threadIdx.x;
  const int w = tid >> 6;
  const int lane = tid & 63;
  const int lo = lane & 15, hi = lane >> 4;
  const char* embB = (const char*)embN;  // 256 B per vocab row (128 bf16)

  // ---- token staging (plain LDS writes) ----
  if (tid < 64) qtok[tid] = query[b * 64 + tid];
  dtok[tid] = doc[b * 256 + tid];

  // ---- stage q tile (wave w: rows 16w..16w+15) + d half 0 (rows 32w..32w+31)
  // LDS layout: row-major 256B rows, 16B slots XOR-swizzled: phys_slot = log_slot ^ (row&7).
  // global_load_lds writes linearly (base + lane*16), so we pre-swizzle the SOURCE slot.
#pragma unroll
  for (int it = 0; it < 4; ++it) {
    int r = w * 16 + it * 4 + hi;
    int tok = query[b * 64 + r];
    int slot = lo ^ (r & 7);
    gld_lds16(embB + (size_t)tok * 256 + slot * 16, qtile + (w * 16 + it * 4) * 256);
  }
#pragma unroll
  for (int it = 0; it < 8; ++it) {
    int rl = w * 32 + it * 4 + hi;  // local dtile row = doc 0..127
    int tok = doc[b * 256 + rl];
    int slot = lo ^ (rl & 7);
    gld_lds16(embB + (size_t)tok * 256 + slot * 16, dtile + (w * 32 + it * 4) * 256);
  }
  asm volatile("s_waitcnt vmcnt(0)" ::: "memory");
  __syncthreads();

  // ---- load Q fragments (B-operand: col = lo = q, k = 8*hi+e), once ----
  bf16x8 bq[4];
#pragma unroll
  for (int kk = 0; kk < 4; ++kk) {
    int slot = (kk * 4 + hi) ^ (lo & 7);
    bq[kk] = *(const bf16x8*)(qtile + (w * 16 + lo) * 256 + slot * 16);
  }

  float acc20[20];
#pragma unroll
  for (int j = 0; j < 20; ++j) acc20[j] = 0.0f;

  const float cA = -50.0f * L2E;   // for |v|*(95-50|v|) exponent (log2 domain)
  const float cB = 95.0f * L2E;
  const float cR = -10.0f * L2E;

#pragma unroll 1
  for (int h = 0; h < 2; ++h) {
    if (h == 1) {
      __syncthreads();  // everyone done reading dtile half 0
#pragma unroll
      for (int it = 0; it < 8; ++it) {
        int rl = w * 32 + it * 4 + hi;
        int tok = doc[b * 256 + 128 + rl];
        int slot = lo ^ (rl & 7);
        gld_lds16(embB + (size_t)tok * 256 + slot * 16, dtile + (w * 32 + it * 4) * 256);
      }
      asm volatile("s_waitcnt vmcnt(0)" ::: "memory");
      __syncthreads();
    }
#pragma unroll
    for (int dr = 0; dr < 8; ++dr) {
      f32x4 mm = {0.0f, 0.0f, 0.0f, 0.0f};
#pragma unroll
      for (int kk = 0; kk < 4; ++kk) {
        int row = dr * 16 + lo;  // doc row (A-operand: row = lo, k = 8*hi+e)
        int slot = (kk * 4 + hi) ^ (lo & 7);
        bf16x8 a = *(const bf16x8*)(dtile + row * 256 + slot * 16);
        mm = __builtin_amdgcn_mfma_f32_16x16x32_bf16(a, bq[kk], mm, 0, 0, 0);
      }
      // mm[e]: doc = 16*dr + 4*hi + e (this half), q = w*16 + lo
#pragma unroll
      for (int e = 0; e < 4; ++e) {
        float v = mm[e];
        float av = fabsf(v);
        float m1 = fmaf(cA, av, cB);       // (95 - 50|v|)*log2e
        float eA = EXP2(m1 * av);          // p at the max-end mu (0.95*sign)
        float r = EXP2(cR * av);           // ratio exp(-10|v|), <= 1
        bool pos = (v >= 0.0f);
        float qq[20];
        qq[0] = eA;
#pragma unroll
        for (int i = 1; i < 20; ++i) qq[i] = qq[i - 1] * r;
#pragma unroll
        for (int j = 0; j < 20; ++j) acc20[j] += pos ? qq[19 - j] : qq[j];
      }
    }
  }

  // ---- exact-match kernel via integer equality (lane covers docs 64*hi..64*hi+63)
  int myq = qtok[w * 16 + lo];
  int cnt = 0;
#pragma unroll 16
  for (int i = 0; i < 64; ++i) cnt += (dtok[hi * 64 + i] == myq) ? 1 : 0;

  // ---- reduce over hi (lanes 16,32 apart share same q) ----
#pragma unroll
  for (int j = 0; j < 20; ++j) {
    acc20[j] += __shfl_xor(acc20[j], 16, 64);
    acc20[j] += __shfl_xor(acc20[j], 32, 64);
  }
  cnt += __shfl_xor(cnt, 16, 64);
  cnt += __shfl_xor(cnt, 32, 64);

  // qtile LDS is dead (bq in regs since before half-0 compute) -> overlay kmbuf
  if (hi == 0) {
    int q = w * 16 + lo;
#pragma unroll
    for (int j = 0; j < 20; ++j) kmbuf[q * 21 + j] = acc20[j];
    kmbuf[q * 21 + 20] = (float)cnt;
  }
  __syncthreads();

  // ---- km[j] = sum_q log1p(C_j * rawsum) ----
  if (tid < 84) {
    int j = tid % 21, c = tid / 21;
    float Cj = 1.0f;
    if (j < 20) {
      float mu = -0.95f + 0.1f * (float)j;
      Cj = EXP2(cA * mu * mu);  // exp(-50*mu^2)
    }
    float s = 0.0f;
    for (int q = 0; q < 16; ++q) s += log1pf(Cj * kmbuf[(c * 16 + q) * 21 + j]);
    km2[c][j] = s;
  }
  __syncthreads();
  if (tid < 21)
    kmv[tid] = fmaxf(km2[0][tid] + km2[1][tid] + km2[2][tid] + km2[3][tid], 0.0f);
  __syncthreads();
  if (tid < 10) {
    float s = b1[tid];
    for (int j = 0; j < 21; ++j) s = fmaf(W1[tid * 21 + j], kmv[j], s);
    x1[tid] = fmaxf(s, 0.0f);
  }
  __syncthreads();
  if (tid < 5) {
    float s = b2[tid];
    for (int i = 0; i < 10; ++i) s = fmaf(W2[tid * 10 + i], x1[i], s);
    x2[tid] = s;
  }
  __syncthreads();
  if (tid == 0) {
    float s = b3[0];
    for (int i = 0; i < 5; ++i) s = fmaf(W3[i], x2[i], s);
    out[b] = s;
  }
}

extern "C" void kernel_launch(void* const* d_in, const int* in_sizes, int n_in,
                              void* d_out, int out_size, void* d_ws, size_t ws_size,
                              hipStream_t stream) {
  const int* query = (const int*)d_in[0];
  const int* doc = (const int*)d_in[1];
  const float* emb = (const float*)d_in[2];
  const float* W1 = (const float*)d_in[3];
  const float* b1 = (const float*)d_in[4];
  const float* W2 = (const float*)d_in[5];
  const float* b2 = (const float*)d_in[6];
  const float* W3 = (const float*)d_in[7];
  const float* b3 = (const float*)d_in[8];
  float* out = (float*)d_out;
  unsigned* embN = (unsigned*)d_ws;  // 50000*64 uints = 12.8 MB bf16 table

  hipLaunchKernelGGL(knrm_norm, dim3(1024), dim3(256), 0, stream, emb, embN);
  hipLaunchKernelGGL(knrm_main, dim3(1024), dim3(256), 0, stream, query, doc, embN,
                     W1, b1, W2, b2, W3, b3, out);
}

// Round 5
// 58.702 us; speedup vs baseline: 7.5884x; 7.5725x over previous
//
#include <hip/hip_runtime.h>
#include <hip/hip_bf16.h>

#define L2E 1.4426950408889634f

#if defined(__has_builtin)
#if __has_builtin(__builtin_amdgcn_exp2f)
#define EXP2(x) __builtin_amdgcn_exp2f(x)
#else
#define EXP2(x) exp2f(x)
#endif
#else
#define EXP2(x) exp2f(x)
#endif

typedef __attribute__((ext_vector_type(8))) short bf16x8;
typedef __attribute__((ext_vector_type(4))) float f32x4;

__device__ __forceinline__ void gld_lds16(const void* g, void* l) {
  __builtin_amdgcn_global_load_lds(
      (const __attribute__((address_space(1))) void*)g,
      (__attribute__((address_space(3))) void*)l, 16, 0, 0);
}

__device__ __forceinline__ unsigned bf16rne(float f) {
  unsigned u = __float_as_uint(f);
  return (u + 0x7fffu + ((u >> 16) & 1u)) >> 16;
}

// Kernel A: L2-normalize embedding table -> packed bf16 (2 per uint32).
__global__ __launch_bounds__(256) void knrm_norm(const float* __restrict__ emb,
                                                 unsigned* __restrict__ embN) {
  const int lane = threadIdx.x & 63;
  int gw = blockIdx.x * 4 + (threadIdx.x >> 6);
  const int nW = gridDim.x * 4;
  for (int r = gw; r < 50000; r += nW) {
    float2 v = *(const float2*)(emb + (size_t)r * 128 + lane * 2);
    float ss = v.x * v.x + v.y * v.y;
#pragma unroll
    for (int m = 1; m < 64; m <<= 1) ss += __shfl_xor(ss, m, 64);
    float sc = 1.0f / fmaxf(sqrtf(ss), 1e-12f);
    embN[(size_t)r * 64 + lane] = bf16rne(v.x * sc) | (bf16rne(v.y * sc) << 16);
  }
}

// Kernel B: per batch item. Docs staged in 64-row quarters (double-buffered
// LDS via global_load_lds), Q fragments direct global->reg. mm^T via
// mfma_f32_16x16x32_bf16. 20 Gaussian kernels via middle-out geometric chain
// (no local arrays -> no scratch). Exact-match kernel = integer token compare.
__global__ __launch_bounds__(256, 4) void knrm_main(
    const int* __restrict__ query, const int* __restrict__ doc,
    const unsigned* __restrict__ embN,
    const float* __restrict__ W1, const float* __restrict__ b1,
    const float* __restrict__ W2, const float* __restrict__ b2,
    const float* __restrict__ W3, const float* __restrict__ b3,
    float* __restrict__ out) {
  __shared__ __align__(16) char dbuf[2][64 * 256];  // 2 x 16KB doc quarters
  __shared__ float kmbuf[64 * 21];
  __shared__ int dtok[256];
  __shared__ float km2[4][21];
  __shared__ float kmv[21];
  __shared__ float x1[10];
  __shared__ float x2[5];

  const int b = blockIdx.x;
  const int tid = threadIdx.x;
  const int w = tid >> 6;
  const int lane = tid & 63;
  const int lo = lane & 15, hi = lane >> 4;
  const char* embB = (const char*)embN;  // 256 B per vocab row (128 bf16)

  dtok[tid] = doc[b * 256 + tid];

  // ---- Q fragments straight from global (B-operand: col=lo=q, k=8*hi+e) ----
  const int myq = query[b * 64 + w * 16 + lo];
  bf16x8 bq[4];
#pragma unroll
  for (int kk = 0; kk < 4; ++kk)
    bq[kk] = *(const bf16x8*)(embB + (size_t)myq * 256 + kk * 64 + hi * 16);

  // ---- stage doc quarter 0 into dbuf[0] ----
  // LDS rows are 256B; 16B slots XOR-swizzled: LDS[row][s] = G[row][s^(row&7)].
  // global_load_lds writes linearly, so we pre-swizzle the SOURCE slot.
#pragma unroll
  for (int it = 0; it < 4; ++it) {
    int rl = w * 16 + it * 4 + hi;  // local row 0..63
    int tok = doc[b * 256 + rl];
    int slot = lo ^ (rl & 7);
    gld_lds16(embB + (size_t)tok * 256 + slot * 16, dbuf[0] + (w * 16 + it * 4) * 256);
  }
  asm volatile("s_waitcnt vmcnt(0)" ::: "memory");
  __syncthreads();

  float acc20[20];
#pragma unroll
  for (int j = 0; j < 20; ++j) acc20[j] = 0.0f;

#pragma unroll 1
  for (int qtr = 0; qtr < 4; ++qtr) {
    const int cur = qtr & 1;
    // prefetch next quarter into the other buffer (overlaps compute below;
    // safe: last barrier guaranteed everyone finished reading it)
    if (qtr < 3) {
#pragma unroll
      for (int it = 0; it < 4; ++it) {
        int rl = w * 16 + it * 4 + hi;
        int tok = doc[b * 256 + (qtr + 1) * 64 + rl];
        int slot = lo ^ (rl & 7);
        gld_lds16(embB + (size_t)tok * 256 + slot * 16,
                  dbuf[cur ^ 1] + (w * 16 + it * 4) * 256);
      }
    }
#pragma unroll
    for (int dr = 0; dr < 4; ++dr) {
      f32x4 mm = {0.0f, 0.0f, 0.0f, 0.0f};
#pragma unroll
      for (int kk = 0; kk < 4; ++kk) {
        int row = dr * 16 + lo;  // A-operand: row=lo, k=8*hi+e
        int slot = (kk * 4 + hi) ^ (lo & 7);
        bf16x8 a = *(const bf16x8*)(dbuf[cur] + row * 256 + slot * 16);
        mm = __builtin_amdgcn_mfma_f32_16x16x32_bf16(a, bq[kk], mm, 0, 0, 0);
      }
      // mm[e]: doc = qtr*64 + dr*16 + 4*hi + e, q = w*16 + lo
#pragma unroll
      for (int e = 0; e < 4; ++e) {
        float v = mm[e];
        // raw_j = exp(-50v^2 + 100*v*mu_j), mu_j = -0.95 + 0.1j.
        // middle-out chain from j=9 (mu=-0.05): every intermediate <= e^45.1;
        // underflow only at chain tails where true value ~0 (monotone decay).
        float m = v * L2E;
        float a10 = m * 10.0f;                           // 10v*log2e
        float G = EXP2(a10);                             // e^{10v}
        float Gi = EXP2(-a10);                           // e^{-10v}
        float t9 = EXP2(m * fmaf(-50.0f, v, -5.0f));     // e^{-50v^2-5v}
        float tu = t9, td = t9;
        acc20[9] += t9;
#pragma unroll
        for (int j = 10; j < 20; ++j) { tu *= G; acc20[j] += tu; }
#pragma unroll
        for (int j = 8; j >= 0; --j) { td *= Gi; acc20[j] += td; }
      }
    }
    asm volatile("s_waitcnt vmcnt(0)" ::: "memory");  // own prefetch drained
    __syncthreads();                                  // everyone's landed
  }

  // ---- exact-match kernel via integer equality (lane covers docs 64*hi..+63)
  int cnt = 0;
#pragma unroll 16
  for (int i = 0; i < 64; ++i) cnt += (dtok[hi * 64 + i] == myq) ? 1 : 0;
  cnt = (myq == 0) ? 0 : cnt;  // padding row is zero vector -> cosine 0, no match

  // ---- reduce over hi (lanes 16,32 apart share same q) ----
#pragma unroll
  for (int j = 0; j < 20; ++j) {
    acc20[j] += __shfl_xor(acc20[j], 16, 64);
    acc20[j] += __shfl_xor(acc20[j], 32, 64);
  }
  cnt += __shfl_xor(cnt, 16, 64);
  cnt += __shfl_xor(cnt, 32, 64);

  if (hi == 0) {
    int q = w * 16 + lo;
#pragma unroll
    for (int j = 0; j < 20; ++j) kmbuf[q * 21 + j] = acc20[j];
    kmbuf[q * 21 + 20] = (float)cnt;
  }
  __syncthreads();

  // ---- km[j] = sum_q log1p(C_j * rawsum), C_j = exp(-50*mu_j^2) ----
  const float cA = -50.0f * L2E;
  if (tid < 84) {
    int j = tid % 21, c = tid / 21;
    float Cj = 1.0f;
    if (j < 20) {
      float mu = -0.95f + 0.1f * (float)j;
      Cj = EXP2(cA * mu * mu);
    }
    float s = 0.0f;
    for (int q = 0; q < 16; ++q) s += log1pf(Cj * kmbuf[(c * 16 + q) * 21 + j]);
    km2[c][j] = s;
  }
  __syncthreads();
  if (tid < 21)
    kmv[tid] = fmaxf(km2[0][tid] + km2[1][tid] + km2[2][tid] + km2[3][tid], 0.0f);
  __syncthreads();
  if (tid < 10) {
    float s = b1[tid];
    for (int j = 0; j < 21; ++j) s = fmaf(W1[tid * 21 + j], kmv[j], s);
    x1[tid] = fmaxf(s, 0.0f);
  }
  __syncthreads();
  if (tid < 5) {
    float s = b2[tid];
    for (int i = 0; i < 10; ++i) s = fmaf(W2[tid * 10 + i], x1[i], s);
    x2[tid] = s;
  }
  __syncthreads();
  if (tid == 0) {
    float s = b3[0];
    for (int i = 0; i < 5; ++i) s = fmaf(W3[i], x2[i], s);
    out[b] = s;
  }
}

extern "C" void kernel_launch(void* const* d_in, const int* in_sizes, int n_in,
                              void* d_out, int out_size, void* d_ws, size_t ws_size,
                              hipStream_t stream) {
  const int* query = (const int*)d_in[0];
  const int* doc = (const int*)d_in[1];
  const float* emb = (const float*)d_in[2];
  const float* W1 = (const float*)d_in[3];
  const float* b1 = (const float*)d_in[4];
  const float* W2 = (const float*)d_in[5];
  const float* b2 = (const float*)d_in[6];
  const float* W3 = (const float*)d_in[7];
  const float* b3 = (const float*)d_in[8];
  float* out = (float*)d_out;
  unsigned* embN = (unsigned*)d_ws;  // 50000*64 uints = 12.8 MB bf16 table

  hipLaunchKernelGGL(knrm_norm, dim3(1024), dim3(256), 0, stream, emb, embN);
  hipLaunchKernelGGL(knrm_main, dim3(1024), dim3(256), 0, stream, query, doc, embN,
                     W1, b1, W2, b2, W3, b3, out);
}

// Round 6
// 40.228 us; speedup vs baseline: 11.0732x; 1.4592x over previous
//
#include <hip/hip_runtime.h>
#include <hip/hip_bf16.h>

#define L2E 1.4426950408889634f
#define LN2 0.6931471805599453f

#if defined(__has_builtin)
#if __has_builtin(__builtin_amdgcn_exp2f)
#define EXP2(x) __builtin_amdgcn_exp2f(x)
#else
#define EXP2(x) exp2f(x)
#endif
#if __has_builtin(__builtin_amdgcn_logf)
#define LOG2(x) __builtin_amdgcn_logf(x)
#else
#define LOG2(x) __log2f(x)
#endif
#else
#define EXP2(x) exp2f(x)
#define LOG2(x) __log2f(x)
#endif

typedef __attribute__((ext_vector_type(8))) short bf16x8;
typedef __attribute__((ext_vector_type(4))) float f32x4;
typedef __attribute__((ext_vector_type(2))) float f32x2;

__device__ __forceinline__ void gld_lds16(const void* g, void* l) {
  __builtin_amdgcn_global_load_lds(
      (const __attribute__((address_space(1))) void*)g,
      (__attribute__((address_space(3))) void*)l, 16, 0, 0);
}

__device__ __forceinline__ unsigned bf16rne(float f) {
  unsigned u = __float_as_uint(f);
  return (u + 0x7fffu + ((u >> 16) & 1u)) >> 16;
}

// Kernel A: L2-normalize embedding table -> packed bf16 (2 per uint32).
// float4 loads, 2 rows per wave (lanes 0-31 row r, lanes 32-63 row r+1).
__global__ __launch_bounds__(256) void knrm_norm(const float* __restrict__ emb,
                                                 unsigned* __restrict__ embN) {
  const int t = threadIdx.x;
  const int l = t & 31;
  const int sub = (t >> 5) & 1;
  int wv = blockIdx.x * 4 + (t >> 6);
  const int nW = gridDim.x * 4;
  for (int rp = wv; rp < 25000; rp += nW) {
    int r = rp * 2 + sub;
    float4 v = *(const float4*)(emb + (size_t)r * 128 + l * 4);
    float ss = v.x * v.x + v.y * v.y + v.z * v.z + v.w * v.w;
#pragma unroll
    for (int m = 1; m < 32; m <<= 1) ss += __shfl_xor(ss, m, 64);  // within 32-lane half
    float sc = 1.0f / fmaxf(sqrtf(ss), 1e-12f);
    uint2 o;
    o.x = bf16rne(v.x * sc) | (bf16rne(v.y * sc) << 16);
    o.y = bf16rne(v.z * sc) | (bf16rne(v.w * sc) << 16);
    *(uint2*)(embN + (size_t)r * 64 + l * 2) = o;
  }
}

// Kernel B: per batch item. Docs staged in 64-row quarters (double-buffered
// LDS via global_load_lds), Q fragments direct global->reg. mm^T via
// mfma_f32_16x16x32_bf16. 20 Gaussian kernels via middle-out geometric chain,
// PACKED f32x2 (two mm elements per chain) -> v_pk_mul/v_pk_add.
// Exact-match kernel = integer token compare. log1p via native v_log_f32.
__global__ __launch_bounds__(256, 4) void knrm_main(
    const int* __restrict__ query, const int* __restrict__ doc,
    const unsigned* __restrict__ embN,
    const float* __restrict__ W1, const float* __restrict__ b1,
    const float* __restrict__ W2, const float* __restrict__ b2,
    const float* __restrict__ W3, const float* __restrict__ b3,
    float* __restrict__ out) {
  __shared__ __align__(16) char dbuf[2][64 * 256];  // 2 x 16KB doc quarters
  __shared__ float kmbuf[64 * 21];
  __shared__ int dtok[256];
  __shared__ float km2[4][21];
  __shared__ float kmv[21];
  __shared__ float x1[10];
  __shared__ float x2[5];

  const int b = blockIdx.x;
  const int tid = threadIdx.x;
  const int w = tid >> 6;
  const int lane = tid & 63;
  const int lo = lane & 15, hi = lane >> 4;
  const char* embB = (const char*)embN;  // 256 B per vocab row (128 bf16)

  dtok[tid] = doc[b * 256 + tid];

  // ---- Q fragments straight from global (B-operand: col=lo=q, k=8*hi+e) ----
  const int myq = query[b * 64 + w * 16 + lo];
  bf16x8 bq[4];
#pragma unroll
  for (int kk = 0; kk < 4; ++kk)
    bq[kk] = *(const bf16x8*)(embB + (size_t)myq * 256 + kk * 64 + hi * 16);

  // ---- stage doc quarter 0 into dbuf[0] ----
  // LDS rows are 256B; 16B slots XOR-swizzled: LDS[row][s] = G[row][s^(row&7)].
  // global_load_lds writes linearly, so we pre-swizzle the SOURCE slot.
#pragma unroll
  for (int it = 0; it < 4; ++it) {
    int rl = w * 16 + it * 4 + hi;  // local row 0..63
    int tok = doc[b * 256 + rl];
    int slot = lo ^ (rl & 7);
    gld_lds16(embB + (size_t)tok * 256 + slot * 16, dbuf[0] + (w * 16 + it * 4) * 256);
  }
  asm volatile("s_waitcnt vmcnt(0)" ::: "memory");
  __syncthreads();

  f32x2 acc20[20];  // packed accumulators: .x sums elems (e=0,2), .y (e=1,3)
#pragma unroll
  for (int j = 0; j < 20; ++j) acc20[j] = (f32x2){0.0f, 0.0f};

#pragma unroll 1
  for (int qtr = 0; qtr < 4; ++qtr) {
    const int cur = qtr & 1;
    // prefetch next quarter into the other buffer (overlaps compute below)
    if (qtr < 3) {
#pragma unroll
      for (int it = 0; it < 4; ++it) {
        int rl = w * 16 + it * 4 + hi;
        int tok = doc[b * 256 + (qtr + 1) * 64 + rl];
        int slot = lo ^ (rl & 7);
        gld_lds16(embB + (size_t)tok * 256 + slot * 16,
                  dbuf[cur ^ 1] + (w * 16 + it * 4) * 256);
      }
    }
#pragma unroll
    for (int dr = 0; dr < 4; ++dr) {
      f32x4 mm = {0.0f, 0.0f, 0.0f, 0.0f};
#pragma unroll
      for (int kk = 0; kk < 4; ++kk) {
        int row = dr * 16 + lo;  // A-operand: row=lo, k=8*hi+e
        int slot = (kk * 4 + hi) ^ (lo & 7);
        bf16x8 a = *(const bf16x8*)(dbuf[cur] + row * 256 + slot * 16);
        mm = __builtin_amdgcn_mfma_f32_16x16x32_bf16(a, bq[kk], mm, 0, 0, 0);
      }
      // mm[e]: doc = qtr*64 + dr*16 + 4*hi + e, q = w*16 + lo
      // raw_j = exp(-50v^2 + 100*v*mu_j), mu_j = -0.95 + 0.1j.
      // middle-out chain from j=9 (mu=-0.05): intermediates <= e^45.1;
      // underflow only at tails where true value ~0. Two packed chains
      // cover the 4 elements -> v_pk_mul_f32 / v_pk_add_f32.
#pragma unroll
      for (int p = 0; p < 2; ++p) {
        f32x2 v = {mm[p], mm[p + 2]};
        f32x2 m = v * L2E;
        f32x2 a10 = m * 10.0f;
        f32x2 G, Gi, t9;
        G.x = EXP2(a10.x);
        G.y = EXP2(a10.y);
        Gi.x = EXP2(-a10.x);
        Gi.y = EXP2(-a10.y);
        f32x2 e9 = m * (v * -50.0f - 5.0f);  // (-50v^2-5v)*log2e
        t9.x = EXP2(e9.x);
        t9.y = EXP2(e9.y);
        f32x2 tu = t9, td = t9;
        acc20[9] += t9;
#pragma unroll
        for (int j = 10; j < 20; ++j) { tu *= G; acc20[j] += tu; }
#pragma unroll
        for (int j = 8; j >= 0; --j) { td *= Gi; acc20[j] += td; }
      }
    }
    asm volatile("s_waitcnt vmcnt(0)" ::: "memory");  // own prefetch drained
    __syncthreads();                                  // everyone's landed
  }

  // ---- exact-match kernel via integer equality (lane covers docs 64*hi..+63)
  int cnt = 0;
#pragma unroll 16
  for (int i = 0; i < 64; ++i) cnt += (dtok[hi * 64 + i] == myq) ? 1 : 0;
  cnt = (myq == 0) ? 0 : cnt;  // padding row is zero vector -> cosine 0, no match

  // ---- horizontal fold + reduce over hi (lanes 16,32 apart share same q) ----
  float sa[20];
#pragma unroll
  for (int j = 0; j < 20; ++j) {
    float s = acc20[j].x + acc20[j].y;
    s += __shfl_xor(s, 16, 64);
    s += __shfl_xor(s, 32, 64);
    sa[j] = s;
  }
  cnt += __shfl_xor(cnt, 16, 64);
  cnt += __shfl_xor(cnt, 32, 64);

  if (hi == 0) {
    int q = w * 16 + lo;
#pragma unroll
    for (int j = 0; j < 20; ++j) kmbuf[q * 21 + j] = sa[j];
    kmbuf[q * 21 + 20] = (float)cnt;
  }
  __syncthreads();

  // ---- km[j] = sum_q log(1 + C_j*rawsum) via native log2, C_j = exp(-50 mu^2)
  const float cA = -50.0f * L2E;
  if (tid < 84) {
    int j = tid % 21, c = tid / 21;
    float Cj = 1.0f;
    if (j < 20) {
      float mu = -0.95f + 0.1f * (float)j;
      Cj = EXP2(cA * mu * mu);
    }
    float s = 0.0f;
    for (int q = 0; q < 16; ++q)
      s += LOG2(fmaf(Cj, kmbuf[(c * 16 + q) * 21 + j], 1.0f));
    km2[c][j] = s * LN2;
  }
  __syncthreads();
  if (tid < 21)
    kmv[tid] = fmaxf(km2[0][tid] + km2[1][tid] + km2[2][tid] + km2[3][tid], 0.0f);
  __syncthreads();
  if (tid < 10) {
    float s = b1[tid];
    for (int j = 0; j < 21; ++j) s = fmaf(W1[tid * 21 + j], kmv[j], s);
    x1[tid] = fmaxf(s, 0.0f);
  }
  __syncthreads();
  if (tid < 5) {
    float s = b2[tid];
    for (int i = 0; i < 10; ++i) s = fmaf(W2[tid * 10 + i], x1[i], s);
    x2[tid] = s;
  }
  __syncthreads();
  if (tid == 0) {
    float s = b3[0];
    for (int i = 0; i < 5; ++i) s = fmaf(W3[i], x2[i], s);
    out[b] = s;
  }
}

extern "C" void kernel_launch(void* const* d_in, const int* in_sizes, int n_in,
                              void* d_out, int out_size, void* d_ws, size_t ws_size,
                              hipStream_t stream) {
  const int* query = (const int*)d_in[0];
  const int* doc = (const int*)d_in[1];
  const float* emb = (const float*)d_in[2];
  const float* W1 = (const float*)d_in[3];
  const float* b1 = (const float*)d_in[4];
  const float* W2 = (const float*)d_in[5];
  const float* b2 = (const float*)d_in[6];
  const float* W3 = (const float*)d_in[7];
  const float* b3 = (const float*)d_in[8];
  float* out = (float*)d_out;
  unsigned* embN = (unsigned*)d_ws;  // 50000*64 uints = 12.8 MB bf16 table

  hipLaunchKernelGGL(knrm_norm, dim3(1024), dim3(256), 0, stream, emb, embN);
  hipLaunchKernelGGL(knrm_main, dim3(1024), dim3(256), 0, stream, query, doc, embN,
                     W1, b1, W2, b2, W3, b3, out);
}